// Round 14
// baseline (463.950 us; speedup 1.0000x reference)
//
#include <hip/hip_runtime.h>
#include <hip/hip_bf16.h>

// Problem dims (fixed)
#define NROWS 8192   // N == M == 8192
#define DIM   512    // IN_FEATS == OUT_FEATS == 512

typedef short v8s __attribute__((ext_vector_type(8)));
typedef float v4f __attribute__((ext_vector_type(4)));

#define ASM_VMCNT(n) asm volatile("s_waitcnt vmcnt(" #n ")" ::: "memory")
#define ASM_LGKM0    asm volatile("s_waitcnt lgkmcnt(0)" ::: "memory")
#define ASM_FENCE    asm volatile("" ::: "memory")
#define BAR          __builtin_amdgcn_s_barrier()

__device__ __forceinline__ short f2bf(float f) {
    union { float f; unsigned u; } v; v.f = f;
    unsigned r = (v.u + 0x7fffu + ((v.u >> 16) & 1u)) >> 16;
    return (short)r;
}

__device__ __forceinline__ void stage16(const void* g, void* l) {
    typedef __attribute__((address_space(1))) const unsigned GA;
    typedef __attribute__((address_space(3))) unsigned LA;
    __builtin_amdgcn_global_load_lds((GA*)(const unsigned*)g, (LA*)(unsigned*)l, 16, 0, 0);
}

// ---------------------------------------------------------------------------
// Cast f32 [R][C] -> bf16 transposed [C][R]  (b128 vectorized writes)
// grid (R/64, C/32), block 256
// ---------------------------------------------------------------------------
__global__ __launch_bounds__(256) void transpose_cast_kernel(
        const float* __restrict__ in, short* __restrict__ out, int R, int C) {
    __shared__ float t[64][33];
    const int r0 = blockIdx.x * 64;
    const int c0 = blockIdx.y * 32;
    const int lrow = threadIdx.x >> 5;
    const int lcol = threadIdx.x & 31;
#pragma unroll
    for (int p = 0; p < 8; ++p)
        t[lrow + 8 * p][lcol] = in[(size_t)(r0 + lrow + 8 * p) * C + c0 + lcol];
    __syncthreads();
    const int oc = threadIdx.x >> 3;
    const int rb = threadIdx.x & 7;
    v8s o;
#pragma unroll
    for (int e = 0; e < 8; ++e) o[e] = f2bf(t[rb * 8 + e][oc]);
    *(v8s*)(out + (size_t)(c0 + oc) * R + r0 + rb * 8) = o;
}

// ---------------------------------------------------------------------------
// H = cast_bf16(F) @ W ; blockIdx.y selects (feat_p -> Hp) / (feat_s -> Hs)
// 256-thr blocks, 64 m-rows x all 512 n-cols, grid (128, 2) = 256 blocks.
// ---------------------------------------------------------------------------
__global__ __launch_bounds__(256) void gemm1_kernel(
        const float* __restrict__ Fp, const float* __restrict__ Fs,
        const short* __restrict__ WT,
        short* __restrict__ Hp, short* __restrict__ Hs) {
    const float* F = blockIdx.y ? Fs : Fp;
    short* H = blockIdx.y ? Hs : Hp;
    const int lane = threadIdx.x & 63;
    const int wid  = threadIdx.x >> 6;
    const int lr = lane & 15, lg = lane >> 4;
    const int r0 = blockIdx.x * 64 + wid * 16;

    v8s a[16];
#pragma unroll
    for (int kk = 0; kk < 16; ++kk) {
        const float* ap = F + (size_t)(r0 + lr) * DIM + kk * 32 + lg * 8;
        float4 f0 = *(const float4*)ap;
        float4 f1 = *(const float4*)(ap + 4);
        v8s t;
        t[0] = f2bf(f0.x); t[1] = f2bf(f0.y); t[2] = f2bf(f0.z); t[3] = f2bf(f0.w);
        t[4] = f2bf(f1.x); t[5] = f2bf(f1.y); t[6] = f2bf(f1.z); t[7] = f2bf(f1.w);
        a[kk] = t;
    }

    for (int ctp = 0; ctp < 16; ++ctp) {
        const int cb = ctp * 32;
        v4f acc0 = {}, acc1 = {};
#pragma unroll
        for (int kk = 0; kk < 16; ++kk) {
            v8s b0 = *(const v8s*)(WT + (size_t)(cb + lr) * DIM + kk * 32 + lg * 8);
            v8s b1 = *(const v8s*)(WT + (size_t)(cb + 16 + lr) * DIM + kk * 32 + lg * 8);
            acc0 = __builtin_amdgcn_mfma_f32_16x16x32_bf16(a[kk], b0, acc0, 0, 0, 0);
            acc1 = __builtin_amdgcn_mfma_f32_16x16x32_bf16(a[kk], b1, acc1, 0, 0, 0);
        }
#pragma unroll
        for (int i = 0; i < 4; ++i) {
            H[(size_t)(r0 + lg * 4 + i) * DIM + cb + lr]      = f2bf(acc0[i]);
            H[(size_t)(r0 + lg * 4 + i) * DIM + cb + 16 + lr] = f2bf(acc1[i]);
        }
    }
}

// ---------------------------------------------------------------------------
// Fused kernel v14: 256-thr blocks, 2 blocks/CU (inter-block overlap).
//   block = 32 m-rows x 32-j steps; grid (256, 2) = 512 blocks = 2/CU.
//   ring[2] = two 32x512 Hs j-tiles (64 KB); Sb[2] = 32x40 bf16 (5 KB).
//   LDS 69 KB/block -> two blocks co-resident; barriers sync only 4 waves,
//   the other block's waves fill the CU during drains (m114 overlap).
// body(t): BAR; stage(t+1); phaseA(t) [16 reads, 2 even/odd chains];
//          relu->Sb[t&1]; vmcnt(8)->phaseB(t-1); lgkm0; issue bF(t);
//          vmcnt(8).   (identical counted-vmcnt arithmetic to R9)
// Phase A wave = (strip=wid>>1: 16 m-rows, half=wid&1: 16 j-cols).
// Phase B wave owns 128 C-cols; accC 16 v4f (64 AGPR).
// ---------------------------------------------------------------------------
#define MTILE  32
#define JSTEP  32
#define JSPLIT 2
#define JT_PER_BLOCK (NROWS / JSTEP / JSPLIT)   // 128

__device__ __forceinline__ void stage_full(const char* __restrict__ HsB,
        char* ringW, int j0, int tid) {
#pragma unroll
    for (int s = 0; s < 8; ++s) {
        const int L = s * 4096 + tid * 16;              // 32 KB, 256 threads
        const int row = L >> 10;                        // 1024 B per j-row
        const int c = (L & 1023) ^ ((row & 7) << 4);    // inverse swizzle
        stage16(HsB + ((size_t)(j0 + row) << 10) + c, ringW + L);
    }
}

__device__ __forceinline__ void load_bF(v8s (&bF)[8], const short* __restrict__ FsT,
        int j, int wid, int lr, int lg) {
#pragma unroll
    for (int ct = 0; ct < 8; ++ct)
        bF[ct] = *(const v8s*)(FsT +
            (size_t)(wid * 128 + ct * 16 + lr) * NROWS + j + lg * 8);
}

__device__ __forceinline__ void phase_b(const short (*SbR)[40], const v8s* bF,
        v4f (&accC)[16], int lr, int lg) {
    __builtin_amdgcn_s_setprio(1);
#pragma unroll
    for (int mt = 0; mt < 2; ++mt) {
        v8s aS = *(const v8s*)&SbR[mt * 16 + lr][lg * 8];
#pragma unroll
        for (int ct = 0; ct < 8; ++ct)
            accC[mt * 8 + ct] = __builtin_amdgcn_mfma_f32_16x16x32_bf16(
                aS, bF[ct], accC[mt * 8 + ct], 0, 0, 0);
    }
    __builtin_amdgcn_s_setprio(0);
}

__global__ __launch_bounds__(256, 2) void fused_kernel(
        const short* __restrict__ Hp, const short* __restrict__ Hs,
        const short* __restrict__ FsT, float* __restrict__ Cacc,
        float* __restrict__ ssq) {
    __shared__ __align__(16) short HsL[2][32][512];   // 2 x 32KB ring
    __shared__ __align__(16) short Sb[2][32][40];     // 2 x 2.5KB S-tile

    const int tid  = threadIdx.x;
    const int lane = tid & 63;
    const int wid  = tid >> 6;                 // 0..3
    const int lr = lane & 15, lg = lane >> 4;
    const int strip = wid >> 1;    // m-strip (0..1), 16 rows
    const int half  = wid & 1;     // j-half (0..1), 16 cols

    // XCD-aware swizzle: 512 blocks, 8 XCDs -> contiguous chunks of 64
    const int nwg = gridDim.x * gridDim.y;
    const int bid = blockIdx.x + gridDim.x * blockIdx.y;
    const int cpx = nwg >> 3;
    const int swz = (bid & 7) * cpx + (bid >> 3);
    const int bx = swz % gridDim.x;
    const int by = swz / gridDim.x;

    const int m0  = bx * MTILE;
    const int jt0 = by * JT_PER_BLOCK;

    // A-fragments: 16 Hp rows (strip) x full K=512 -> 64 VGPR
    v8s afrag[16];
#pragma unroll
    for (int kk = 0; kk < 16; ++kk)
        afrag[kk] = *(const v8s*)(Hp +
            (size_t)(m0 + strip * 16 + lr) * DIM + kk * 32 + lg * 8);

    v4f accC[16] = {};
    v8s bF[8];
    float ssq_l = 0.f;

    stage_full((const char*)Hs, (char*)&HsL[0][0][0], jt0 * JSTEP, tid);
    ASM_VMCNT(0);   // afrag + jt0 staging drained

    const int xo = (lr & 7) << 4;

    for (int t = 0; t < JT_PER_BLOCK; ++t) {
        const int jcur  = (jt0 + t) * JSTEP;
        const int jnext = (t + 1 < JT_PER_BLOCK) ? jcur + JSTEP : jt0 * JSTEP;
        const char* ringR = (const char*)&HsL[t & 1][0][0];
        char*       ringW = (char*)&HsL[(t + 1) & 1][0][0];

        BAR;   // ring[t&1] staged by all; Sb[(t-1)&1] published; readers done
        ASM_FENCE;

        // issue staging for next jt (stays in flight through this body)
        stage_full((const char*)Hs, ringW, jnext, tid);

        // ---- phase A(t): S[strip*16..+16][half*16..+16] over K=512
        //      even/odd kk split -> 2 independent MFMA chains
        v4f sE = {}, sO = {};
        {
            const char* rp = ringR + (size_t)(half * 16 + lr) * 1024;
            __builtin_amdgcn_s_setprio(1);
#pragma unroll
            for (int kp = 0; kp < 8; ++kp) {
                const int k0 = 2 * kp, k1 = 2 * kp + 1;
                v8s hbE = *(const v8s*)(rp + ((k0 * 64 + lg * 16) ^ xo));
                v8s hbO = *(const v8s*)(rp + ((k1 * 64 + lg * 16) ^ xo));
                sE = __builtin_amdgcn_mfma_f32_16x16x32_bf16(afrag[k0], hbE, sE, 0, 0, 0);
                sO = __builtin_amdgcn_mfma_f32_16x16x32_bf16(afrag[k1], hbO, sO, 0, 0, 0);
            }
            __builtin_amdgcn_s_setprio(0);
        }

        // ---- relu + ssq + Sb[t&1] write
        short (*SbW)[40] = Sb[t & 1];
#pragma unroll
        for (int i = 0; i < 4; ++i) {
            float v = fmaxf(sE[i] + sO[i], 0.f);
            ssq_l += v * v;
            SbW[strip * 16 + lg * 4 + i][half * 16 + lr] = f2bf(v);
        }

        // ---- phase B(t-1): bF(t-1) issued last body, landed by now
        if (t > 0) {
            ASM_VMCNT(8);   // drains bF(t-1) (oldest 8); stage(t+1) stays
            phase_b(Sb[(t - 1) & 1], bF, accC, lr, lg);
        }
        ASM_LGKM0;          // ring reads + Sb writes drained

        // ---- issue bF(t) for next body's phase B (rides across the BAR)
        ASM_FENCE;
        load_bF(bF, FsT, jcur, wid, lr, lg);
        ASM_VMCNT(8);       // drains stage(t+1); bF(t) stays in flight
    }

    // ---- final phase B (bF already in flight)
    BAR;
    ASM_VMCNT(0);
    phase_b(Sb[(JT_PER_BLOCK - 1) & 1], bF, accC, lr, lg);

    // ---- epilogue
    float w = ssq_l;
#pragma unroll
    for (int off = 32; off; off >>= 1) w += __shfl_down(w, off);
    if (lane == 0) atomicAdd(ssq, w);

#pragma unroll
    for (int mt = 0; mt < 2; ++mt)
#pragma unroll
        for (int ct = 0; ct < 8; ++ct)
#pragma unroll
            for (int i = 0; i < 4; ++i)
                atomicAdd(&Cacc[(size_t)(m0 + mt * 16 + lg * 4 + i) * DIM +
                                wid * 128 + ct * 16 + lr],
                          accC[mt * 8 + ct][i]);
}

// ---------------------------------------------------------------------------
__global__ __launch_bounds__(256) void scale_kernel(float* __restrict__ C,
                                                    const float* __restrict__ ssq) {
    const float rs = 1.0f / sqrtf(*ssq);
    const size_t i = (size_t)blockIdx.x * blockDim.x + threadIdx.x;
    float4* p = (float4*)C;
    float4 v = p[i];
    v.x *= rs; v.y *= rs; v.z *= rs; v.w *= rs;
    p[i] = v;
}

// ---------------------------------------------------------------------------
extern "C" void kernel_launch(void* const* d_in, const int* in_sizes, int n_in,
                              void* d_out, int out_size, void* d_ws, size_t ws_size,
                              hipStream_t stream) {
    const float* feat_p   = (const float*)d_in[0];
    const float* feat_s   = (const float*)d_in[1];
    const float* weight_a = (const float*)d_in[2];

    char* ws = (char*)d_ws;
    float* ssqp = (float*)ws;                                  // 4 B
    short* WT   = (short*)(ws + 512);                          // 512 KB
    short* Hp   = (short*)(ws + 512 + 524288);                 // 8 MB
    short* Hs   = (short*)(ws + 512 + 524288 + 8388608);       // 8 MB
    short* FsT  = (short*)(ws + 512 + 524288 + 16777216);      // 8 MB [DIM][NROWS]

    transpose_cast_kernel<<<dim3(DIM / 64, DIM / 32), 256, 0, stream>>>(weight_a, WT, DIM, DIM);
    transpose_cast_kernel<<<dim3(NROWS / 64, DIM / 32), 256, 0, stream>>>(feat_s, FsT, NROWS, DIM);

    gemm1_kernel<<<dim3(NROWS / 64, 2), 256, 0, stream>>>(
        feat_p, feat_s, WT, Hp, Hs);

    hipMemsetAsync(d_out, 0, (size_t)out_size * sizeof(float), stream);
    hipMemsetAsync(ssqp, 0, sizeof(float), stream);

    fused_kernel<<<dim3(NROWS / MTILE, JSPLIT), 256, 0, stream>>>(
        Hp, Hs, FsT, (float*)d_out, ssqp);

    scale_kernel<<<(out_size / 4 + 255) / 256, 256, 0, stream>>>((float*)d_out, ssqp);
}